// Round 19
// baseline (262.719 us; speedup 1.0000x reference)
//
#include <hip/hip_runtime.h>
#include <hip/hip_bf16.h>
#include <hip/hip_fp16.h>
#include <hip/hip_cooperative_groups.h>

namespace cg = cooperative_groups;

#define USER_NUM 100000
#define ITEM_NUM 50000
#define NNODES   150000
#define DIM      64
#define NEDGES   2400000
#define BATCH    4096

#define SPN      1024                           // nodes per super-bucket (dst>>10)
#define NSUP     ((NNODES + SPN - 1) / SPN)     // 147 super-buckets
#define NSUPP    160                            // padded stride for blockhist
#define NBLK_C   256                            // coop grid (1 block/CU)
#define CHUNK_C  (NEDGES / NBLK_C)              // 9375 edges per block (exact)
#define SPMM_B   ((NNODES * 8 + 255) / 256)     // 4688
#define SAMP_B   ((2 * BATCH * 16 + 255) / 256) // 512
#define MARK_B   ((2 * BATCH * 16 + 255) / 256) // 512

__device__ inline float4 h4_to_f4(float2 raw) {
    __half2 a = ((__half2*)&raw)[0];
    __half2 b = ((__half2*)&raw)[1];
    float2 fa = __half22float2(a);
    float2 fb = __half22float2(b);
    return make_float4(fa.x, fa.y, fb.x, fb.y);
}

__device__ inline float2 f4_to_h4(float4 s) {
    __half2 a = __floats2half2_rn(s.x, s.y);
    __half2 b = __floats2half2_rn(s.z, s.w);
    float2 st;
    ((__half2*)&st)[0] = a;
    ((__half2*)&st)[1] = b;
    return st;
}

// ---------------------------------------------------------------------------
// Cooperative CSR build + init, 3 phases with grid syncs.
//  P1: per-block hist (own 9375-edge chunk) || init tabA || sample_init acc_s
//  P2: partition into super-bucket-contiguous tmp (LDS-staged, coalesced out)
//  P3: per-super counting sort -> row_ptr + sorted sedge (blocks 0..146)
// ---------------------------------------------------------------------------
__global__ __launch_bounds__(1024) void csr_coop_kernel(
        const int* __restrict__ edge_src,
        const int* __restrict__ edge_dst,
        const float* __restrict__ edge_val,
        const float* __restrict__ user_emb,
        const float* __restrict__ item_emb,
        const int* __restrict__ users,
        const int* __restrict__ items,
        int* __restrict__ bucket_cnt,
        int* __restrict__ blockhist,
        int* __restrict__ fill,
        int2* __restrict__ tmp,
        int* __restrict__ row_ptr,
        int2* __restrict__ sedge,
        __half* __restrict__ tabA,
        float* __restrict__ acc_s) {
    __shared__ int2 sout[CHUNK_C];              // 75 KB
    __shared__ unsigned char sbkt[CHUNK_C];     // 9.2 KB
    __shared__ int cur_[NSUP];
    __shared__ int goff[NSUP];
    __shared__ long scl[256];
    __shared__ int h2[SPN];
    __shared__ int sc2[SPN];
    __shared__ int cur2[SPN];
    __shared__ int gsc[256];
    __shared__ int sbase, send;

    cg::grid_group grid = cg::this_grid();
    int b = blockIdx.x;
    int tid = threadIdx.x;
    int lo = b * CHUNK_C;

    // ---------- Phase 1 ----------
    for (int t = tid; t < NSUP; t += 1024) cur_[t] = 0;
    __syncthreads();
    for (int j = lo + tid; j < lo + CHUNK_C; j += 1024)
        atomicAdd(&cur_[edge_dst[j] >> 10], 1);
    __syncthreads();
    for (int t = tid; t < NSUP; t += 1024) {
        int c = cur_[t];
        blockhist[b * NSUPP + t] = c;
        if (c) atomicAdd(&bucket_cnt[t], c);
    }
    // init fp16 table (grid-stride)
    const long total4 = (long)NNODES * DIM / 4;
    const long user4  = (long)USER_NUM * DIM / 4;
    for (long i = (long)b * 1024 + tid; i < total4; i += (long)NBLK_C * 1024) {
        float4 v;
        if (i < user4) v = ((const float4*)user_emb)[i];
        else           v = ((const float4*)item_emb)[i - user4];
        ((float2*)tabA)[i] = f4_to_h4(v);
    }
    // sample_init: acc_s[slot] = e0
    for (int t = b * 1024 + tid; t < 2 * BATCH * 16; t += NBLK_C * 1024) {
        int slot = t >> 4;
        int k = (t & 15) * 4;
        const float* src = (slot < BATCH)
            ? &user_emb[(long)users[slot] * DIM]
            : &item_emb[(long)items[slot - BATCH] * DIM];
        *(float4*)&acc_s[(long)slot * DIM + k] = *(const float4*)&src[k];
    }
    grid.sync();

    // ---------- Phase 2: partition ----------
    {
        int g = 0, c = 0;
        if (tid < NSUP) {
            g = bucket_cnt[tid];
            c = blockhist[b * NSUPP + tid];
        }
        if (tid < 256) scl[tid] = ((long)g << 32) | (unsigned)c;
        __syncthreads();
        for (int off = 1; off < 256; off <<= 1) {
            long t = (tid >= off && tid < 256) ? scl[tid - off] : 0;
            __syncthreads();
            if (tid < 256) scl[tid] += t;
            __syncthreads();
        }
        if (tid < NSUP) {
            long incl = scl[tid];
            int gincl = (int)(incl >> 32);
            int lincl = (int)(incl & 0xffffffffL);
            int gexcl = gincl - g;       // bucket_base
            int lexcl = lincl - c;       // local base
            cur_[tid] = lexcl;
            goff[tid] = gexcl + (c ? atomicAdd(&fill[tid], c) : 0) - lexcl;
        }
        __syncthreads();
        for (int i = tid; i < CHUNK_C; i += 1024) {
            int d = edge_dst[lo + i];
            int bb = d >> 10;
            int pos = atomicAdd(&cur_[bb], 1);
            sout[pos] = make_int2(__float_as_int(edge_val[lo + i]),
                                  edge_src[lo + i] | ((d & (SPN - 1)) << 18));
            sbkt[pos] = (unsigned char)bb;
        }
        __syncthreads();
        for (int i = tid; i < CHUNK_C; i += 1024) {
            int bb = sbkt[i];
            tmp[goff[bb] + i] = sout[i];
        }
    }
    grid.sync();

    // ---------- Phase 3: local sort (blocks 0..NSUP-1) ----------
    if (b < NSUP) {
        int g = (tid < NSUP) ? bucket_cnt[tid] : 0;
        if (tid < 256) gsc[tid] = g;
        __syncthreads();
        for (int off = 1; off < 256; off <<= 1) {
            int t = (tid >= off && tid < 256) ? gsc[tid - off] : 0;
            __syncthreads();
            if (tid < 256) gsc[tid] += t;
            __syncthreads();
        }
        if (tid == 0) {
            int incl = gsc[b];
            int cb = bucket_cnt[b];
            sbase = incl - cb;
            send = incl;
            if (b == 0) row_ptr[NNODES] = NEDGES;
        }
        h2[tid] = 0;
        __syncthreads();
        int base = sbase, end = send;
        for (int j = base + tid; j < end; j += 1024)
            atomicAdd(&h2[(tmp[j].y >> 18) & (SPN - 1)], 1);
        __syncthreads();
        int c = h2[tid];
        sc2[tid] = c;
        __syncthreads();
        for (int off = 1; off < SPN; off <<= 1) {
            int t = (tid >= off) ? sc2[tid - off] : 0;
            __syncthreads();
            sc2[tid] += t;
            __syncthreads();
        }
        int excl = sc2[tid] - c;
        cur2[tid] = base + excl;
        int node = b * SPN + tid;
        if (node < NNODES) row_ptr[node] = base + excl;
        __syncthreads();
        for (int j = base + tid; j < end; j += 1024) {
            int2 e = tmp[j];
            int dl = (e.y >> 18) & (SPN - 1);
            int pos = atomicAdd(&cur2[dl], 1);
            sedge[pos] = make_int2(e.y & 0x3FFFF, e.x);   // (src, val_bits)
        }
    }
}

// ---------------------------------------------------------------------------
// spmm row body: 8 lanes per dst row, 16 B per lane, unroll x4
// ---------------------------------------------------------------------------
__device__ inline void spmm_row(int row, int k,
                                const int* __restrict__ row_ptr,
                                const int2* __restrict__ sedge,
                                const __half* __restrict__ cur,
                                __half* __restrict__ next) {
    int start = row_ptr[row];
    int end   = row_ptr[row + 1];
    float a0[8], a1[8], a2[8], a3[8];
    #pragma unroll
    for (int q = 0; q < 8; ++q) { a0[q] = 0.f; a1[q] = 0.f; a2[q] = 0.f; a3[q] = 0.f; }
    int j = start;
    for (; j + 4 <= end; j += 4) {
        int2 e0 = sedge[j];
        int2 e1 = sedge[j + 1];
        int2 e2 = sedge[j + 2];
        int2 e3 = sedge[j + 3];
        float4 r0 = *(const float4*)&cur[(long)e0.x * DIM + k];
        float4 r1 = *(const float4*)&cur[(long)e1.x * DIM + k];
        float4 r2 = *(const float4*)&cur[(long)e2.x * DIM + k];
        float4 r3 = *(const float4*)&cur[(long)e3.x * DIM + k];
        float v0 = __int_as_float(e0.y), v1 = __int_as_float(e1.y);
        float v2 = __int_as_float(e2.y), v3 = __int_as_float(e3.y);
        const __half2* h0 = (const __half2*)&r0;
        const __half2* h1 = (const __half2*)&r1;
        const __half2* h2 = (const __half2*)&r2;
        const __half2* h3 = (const __half2*)&r3;
        #pragma unroll
        for (int q = 0; q < 4; ++q) {
            float2 f0 = __half22float2(h0[q]);
            float2 f1 = __half22float2(h1[q]);
            float2 f2 = __half22float2(h2[q]);
            float2 f3 = __half22float2(h3[q]);
            a0[2*q]   += v0 * f0.x;  a0[2*q+1] += v0 * f0.y;
            a1[2*q]   += v1 * f1.x;  a1[2*q+1] += v1 * f1.y;
            a2[2*q]   += v2 * f2.x;  a2[2*q+1] += v2 * f2.y;
            a3[2*q]   += v3 * f3.x;  a3[2*q+1] += v3 * f3.y;
        }
    }
    for (; j < end; ++j) {
        int2 e = sedge[j];
        float v = __int_as_float(e.y);
        float4 r = *(const float4*)&cur[(long)e.x * DIM + k];
        const __half2* h = (const __half2*)&r;
        #pragma unroll
        for (int q = 0; q < 4; ++q) {
            float2 f = __half22float2(h[q]);
            a0[2*q]   += v * f.x;
            a0[2*q+1] += v * f.y;
        }
    }
    float4 st;
    __half2* sh = (__half2*)&st;
    #pragma unroll
    for (int q = 0; q < 4; ++q) {
        float lo = (a0[2*q]   + a1[2*q])   + (a2[2*q]   + a3[2*q]);
        float hi = (a0[2*q+1] + a1[2*q+1]) + (a2[2*q+1] + a3[2*q+1]);
        sh[q] = __floats2half2_rn(lo, hi);
    }
    *(float4*)&next[(long)row * DIM + k] = st;
}

// ---------------------------------------------------------------------------
// Layer 1 + mark tail: plain (non-atomic) flag stores.
// ---------------------------------------------------------------------------
__global__ void spmm_mark_kernel(const int* __restrict__ row_ptr,
                                 const int2* __restrict__ sedge,
                                 const __half* __restrict__ cur,
                                 __half* __restrict__ next,
                                 const int* __restrict__ users,
                                 const int* __restrict__ items,
                                 int* __restrict__ flags) {
    if (blockIdx.x < SPMM_B) {
        long t = (long)blockIdx.x * 256 + threadIdx.x;
        int row = (int)(t >> 3);
        if (row >= NNODES) return;
        spmm_row(row, ((int)t & 7) * 8, row_ptr, sedge, cur, next);
    } else {
        int t = (blockIdx.x - SPMM_B) * 256 + threadIdx.x;
        int slot = t >> 4;
        if (slot >= 2 * BATCH) return;
        int lane16 = t & 15;
        int node = (slot < BATCH) ? users[slot] : USER_NUM + items[slot - BATCH];
        if (lane16 == 0) flags[node] = 1;        // plain store
        int start = row_ptr[node];
        int end   = row_ptr[node + 1];
        for (int j = start + lane16; j < end; j += 16)
            flags[sedge[j].x] = 1;               // plain store, dup-safe
    }
}

// ---------------------------------------------------------------------------
// Layer 2 flag-gated + sample_add(e1) tail.
// ---------------------------------------------------------------------------
__global__ void spmm_flag_sa_kernel(const int* __restrict__ row_ptr,
                                    const int2* __restrict__ sedge,
                                    const __half* __restrict__ cur,
                                    __half* __restrict__ next,
                                    const int* __restrict__ users,
                                    const int* __restrict__ items,
                                    float* __restrict__ acc_s,
                                    const int* __restrict__ flags) {
    if (blockIdx.x < SPMM_B) {
        long t = (long)blockIdx.x * 256 + threadIdx.x;
        int row = (int)(t >> 3);
        if (row >= NNODES) return;
        if (!flags[row]) return;                 // e2 not needed here
        spmm_row(row, ((int)t & 7) * 8, row_ptr, sedge, cur, next);
    } else {
        int t = (blockIdx.x - SPMM_B) * 256 + threadIdx.x;
        int slot = t >> 4;
        if (slot >= 2 * BATCH) return;
        int k = (t & 15) * 4;
        int node = (slot < BATCH) ? users[slot] : USER_NUM + items[slot - BATCH];
        float4 x = h4_to_f4(*(const float2*)&cur[(long)node * DIM + k]);
        long o = (long)slot * DIM + k;
        float4 a = *(float4*)&acc_s[o];
        a.x += x.x; a.y += x.y; a.z += x.z; a.w += x.w;
        *(float4*)&acc_s[o] = a;
    }
}

// ---------------------------------------------------------------------------
// pair_kernel: fuse sample_add(e2) + sampled e3 + dot + sigmoid.
// ---------------------------------------------------------------------------
__global__ __launch_bounds__(256) void pair_kernel(
        const int* __restrict__ row_ptr,
        const int2* __restrict__ sedge,
        const __half* __restrict__ tab,     // e2 table (valid at flagged rows)
        const int* __restrict__ users,
        const int* __restrict__ items,
        const float* __restrict__ acc_s,    // e0+e1
        float* __restrict__ out) {
    int t = blockIdx.x * 256 + threadIdx.x;
    int p = t >> 5;
    if (p >= BATCH) return;
    int sub = t & 31;
    int lane = threadIdx.x & 63;
    bool isU = (sub < 16);
    int k = (sub & 15) * 4;
    int node = isU ? users[p] : USER_NUM + items[p];
    int slot = isU ? p : BATCH + p;

    int start = row_ptr[node];
    int end   = row_ptr[node + 1];
    float4 s0 = make_float4(0.f, 0.f, 0.f, 0.f);
    float4 s1 = s0;
    int j = start;
    for (; j + 2 <= end; j += 2) {
        int2 e0 = sedge[j];
        int2 e1 = sedge[j + 1];
        float4 x0 = h4_to_f4(*(const float2*)&tab[(long)e0.x * DIM + k]);
        float4 x1 = h4_to_f4(*(const float2*)&tab[(long)e1.x * DIM + k]);
        float v0 = __int_as_float(e0.y), v1 = __int_as_float(e1.y);
        s0.x += v0 * x0.x; s0.y += v0 * x0.y; s0.z += v0 * x0.z; s0.w += v0 * x0.w;
        s1.x += v1 * x1.x; s1.y += v1 * x1.y; s1.z += v1 * x1.z; s1.w += v1 * x1.w;
    }
    for (; j < end; ++j) {
        int2 e = sedge[j];
        float v = __int_as_float(e.y);
        float4 x = h4_to_f4(*(const float2*)&tab[(long)e.x * DIM + k]);
        s0.x += v * x.x; s0.y += v * x.y; s0.z += v * x.z; s0.w += v * x.w;
    }
    float4 a = *(const float4*)&acc_s[(long)slot * DIM + k];
    float4 e2v = h4_to_f4(*(const float2*)&tab[(long)node * DIM + k]);
    a.x += e2v.x + s0.x + s1.x;
    a.y += e2v.y + s0.y + s1.y;
    a.z += e2v.z + s0.z + s1.z;
    a.w += e2v.w + s0.w + s1.w;

    int partner = (lane + 16) & 63;
    float bx = __shfl(a.x, partner);
    float by = __shfl(a.y, partner);
    float bz = __shfl(a.z, partner);
    float bw = __shfl(a.w, partner);
    float pd = a.x * bx + a.y * by + a.z * bz + a.w * bw;
    #pragma unroll
    for (int off = 1; off < 16; off <<= 1) pd += __shfl_xor(pd, off);
    if (sub == 0) {
        float gamma = pd * (1.0f / 16.0f);
        out[p] = 1.0f / (1.0f + __expf(-gamma));
    }
}

extern "C" void kernel_launch(void* const* d_in, const int* in_sizes, int n_in,
                              void* d_out, int out_size, void* d_ws, size_t ws_size,
                              hipStream_t stream) {
    const int*   edge_src = (const int*)d_in[2];
    const int*   edge_dst = (const int*)d_in[3];
    const float* edge_val = (const float*)d_in[4];
    const float* user_emb = (const float*)d_in[0];
    const float* item_emb = (const float*)d_in[1];
    const int*   users    = (const int*)d_in[5];
    const int*   items    = (const int*)d_in[6];
    float* out = (float*)d_out;

    const size_t tbl  = (size_t)NNODES * DIM * sizeof(float);   // 38.4 MB
    const size_t htbl = (size_t)NNODES * DIM * sizeof(__half);  // 19.2 MB
    char* w = (char*)d_ws;
    float*  acc_s       = (float*)w;   w += tbl;
    char*   bufA        = w;           w += tbl;   // tmp int2, dead after coop
    char*   bufB        = w;           w += tbl;   // tabA + tabB
    int2*   sedge       = (int2*)w;    w += (size_t)NEDGES * 8;
    int*    row_ptr     = (int*)w;     w += ((size_t)NNODES + 16) * 4;
    // zeroed region: bucket_cnt | fill | flags  (one memset)
    int*    bucket_cnt  = (int*)w;     w += ((size_t)NSUP + 8) * 4;
    int*    fill        = (int*)w;     w += ((size_t)NSUP + 8) * 4;
    int*    flags       = (int*)w;     w += (size_t)NNODES * 4;
    const size_t zero_bytes = (size_t)((char*)w - (char*)bucket_cnt);
    int*    blockhist   = (int*)w;     w += (size_t)NBLK_C * NSUPP * 4;  // 160 KB

    int2*   tmp   = (int2*)bufA;
    __half* tabA  = (__half*)bufB;
    __half* tabB  = (__half*)(bufB + htbl);

    // ---- memset: bucket_cnt + fill + flags ----
    hipMemsetAsync(bucket_cnt, 0, zero_bytes, stream);

    // ---- cooperative CSR build + init (3 phases, 2 grid syncs) ----
    void* args[] = {
        (void*)&edge_src, (void*)&edge_dst, (void*)&edge_val,
        (void*)&user_emb, (void*)&item_emb, (void*)&users, (void*)&items,
        (void*)&bucket_cnt, (void*)&blockhist, (void*)&fill,
        (void*)&tmp, (void*)&row_ptr, (void*)&sedge,
        (void*)&tabA, (void*)&acc_s
    };
    hipLaunchCooperativeKernel((void*)csr_coop_kernel, dim3(NBLK_C), dim3(1024),
                               args, 0, stream);

    // ---- layer 1 (full) + plain-store mark tail ----
    spmm_mark_kernel<<<SPMM_B + MARK_B, 256, 0, stream>>>(
        row_ptr, sedge, tabA, tabB, users, items, flags);
    // ---- layer 2 flag-gated + sample_add(e1) tail ----
    spmm_flag_sa_kernel<<<SPMM_B + SAMP_B, 256, 0, stream>>>(
        row_ptr, sedge, tabB, tabA, users, items, acc_s, flags);
    // ---- sample_add(e2) + sampled e3 + dot + sigmoid ----
    pair_kernel<<<(BATCH * 32 + 255) / 256, 256, 0, stream>>>(
        row_ptr, sedge, tabA, users, items, acc_s, out);
}

// Round 20
// 190.930 us; speedup vs baseline: 1.3760x; 1.3760x over previous
//
#include <hip/hip_runtime.h>
#include <hip/hip_bf16.h>
#include <hip/hip_fp16.h>

#define USER_NUM 100000
#define ITEM_NUM 50000
#define NNODES   150000
#define DIM      64
#define NEDGES   2400000
#define BATCH    4096

#define SPN      1024                           // nodes per super-bucket (dst>>10)
#define NSUP     ((NNODES + SPN - 1) / SPN)     // 147 super-buckets
#define NSUPP    160                            // padded stride for blockhist
#define CHUNK    4096
#define NBLK     ((NEDGES + CHUNK - 1) / CHUNK) // 586 blocks
#define INIT_B   ((NNODES * DIM / 4 + 255) / 256)   // 9375
#define SAMP_B   ((2 * BATCH * 16 + 255) / 256)     // 512
#define SPMM_B   ((NNODES * 8 + 255) / 256)         // 4688
#define MARK_B   ((2 * BATCH * 16 + 255) / 256)     // 512 (16 thr/row)

__device__ inline float4 h4_to_f4(float2 raw) {
    __half2 a = ((__half2*)&raw)[0];
    __half2 b = ((__half2*)&raw)[1];
    float2 fa = __half22float2(a);
    float2 fb = __half22float2(b);
    return make_float4(fa.x, fa.y, fb.x, fb.y);
}

__device__ inline float2 f4_to_h4(float4 s) {
    __half2 a = __floats2half2_rn(s.x, s.y);
    __half2 b = __floats2half2_rn(s.z, s.w);
    float2 st;
    ((__half2*)&st)[0] = a;
    ((__half2*)&st)[1] = b;
    return st;
}

// ---------------------------------------------------------------------------
// MEGA1: blocks [0,NBLK): bucket hist; [NBLK,+INIT_B): init tabA;
//        [NBLK+INIT_B,+SAMP_B): sample_init acc_s. All independent.
// ---------------------------------------------------------------------------
__global__ __launch_bounds__(256) void mega1_kernel(
        const int* __restrict__ edge_dst,
        int* __restrict__ bucket_cnt,
        int* __restrict__ blockhist,
        const float* __restrict__ user_emb,
        const float* __restrict__ item_emb,
        __half* __restrict__ curh,
        const int* __restrict__ users,
        const int* __restrict__ items,
        float* __restrict__ acc_s) {
    __shared__ int h[NSUP];
    int b = blockIdx.x;
    if (b < NBLK) {
        for (int t = threadIdx.x; t < NSUP; t += blockDim.x) h[t] = 0;
        __syncthreads();
        int lo = b * CHUNK;
        int hi = min(lo + CHUNK, NEDGES);
        for (int j = lo + (int)threadIdx.x; j < hi; j += blockDim.x)
            atomicAdd(&h[edge_dst[j] >> 10], 1);
        __syncthreads();
        for (int t = threadIdx.x; t < NSUP; t += blockDim.x) {
            int c = h[t];
            blockhist[b * NSUPP + t] = c;
            if (c) atomicAdd(&bucket_cnt[t], c);
        }
    } else if (b < NBLK + INIT_B) {
        const long total4 = (long)NNODES * DIM / 4;
        long i = (long)(b - NBLK) * 256 + threadIdx.x;
        if (i >= total4) return;
        const long user4 = (long)USER_NUM * DIM / 4;
        float4 v;
        if (i < user4) v = ((const float4*)user_emb)[i];
        else           v = ((const float4*)item_emb)[i - user4];
        ((float2*)curh)[i] = f4_to_h4(v);
    } else {
        int t = (b - NBLK - INIT_B) * 256 + threadIdx.x;
        int slot = t >> 4;
        if (slot >= 2 * BATCH) return;
        int k = (t & 15) * 4;
        const float* src = (slot < BATCH)
            ? &user_emb[(long)users[slot] * DIM]
            : &item_emb[(long)items[slot - BATCH] * DIM];
        *(float4*)&acc_s[(long)slot * DIM + k] = *(const float4*)&src[k];
    }
}

// ---------------------------------------------------------------------------
// K4: partition, 1024 threads, LDS-staged, coalesced copy-out, inline scan.
// ---------------------------------------------------------------------------
__global__ __launch_bounds__(1024) void partition_kernel(
        const int* __restrict__ edge_src,
        const int* __restrict__ edge_dst,
        const float* __restrict__ edge_val,
        const int* __restrict__ blockhist,
        const int* __restrict__ bucket_cnt,
        int* __restrict__ fill,
        int2* __restrict__ tmp) {
    __shared__ int cur_[NSUP];
    __shared__ int goff[NSUP];
    __shared__ long scl[256];
    __shared__ unsigned char sbkt[CHUNK];   // 4 KB
    __shared__ int2 sout[CHUNK];            // 32 KB
    int tid = threadIdx.x;
    int lo = blockIdx.x * CHUNK;
    int hi = min(lo + CHUNK, NEDGES);
    int n = hi - lo;

    int g = 0, c = 0;
    if (tid < NSUP) {
        g = bucket_cnt[tid];
        c = blockhist[blockIdx.x * NSUPP + tid];
    }
    if (tid < 256) scl[tid] = ((long)g << 32) | (unsigned)c;
    __syncthreads();
    for (int off = 1; off < 256; off <<= 1) {
        long t = (tid >= off && tid < 256) ? scl[tid - off] : 0;
        __syncthreads();
        if (tid < 256) scl[tid] += t;
        __syncthreads();
    }
    if (tid < NSUP) {
        long incl = scl[tid];
        int gincl = (int)(incl >> 32);
        int lincl = (int)(incl & 0xffffffffL);
        int gexcl = gincl - g;
        int lexcl = lincl - c;
        cur_[tid] = lexcl;
        goff[tid] = gexcl + (c ? atomicAdd(&fill[tid], c) : 0) - lexcl;
    }
    __syncthreads();
    for (int i = tid; i < n; i += 1024) {
        int d = edge_dst[lo + i];
        int b = d >> 10;
        int pos = atomicAdd(&cur_[b], 1);
        sout[pos] = make_int2(__float_as_int(edge_val[lo + i]),
                              edge_src[lo + i] | ((d & (SPN - 1)) << 18));
        sbkt[pos] = (unsigned char)b;
    }
    __syncthreads();
    for (int i = tid; i < n; i += 1024) {
        int b = sbkt[i];
        tmp[goff[b] + i] = sout[i];
    }
}

// ---------------------------------------------------------------------------
// K5: per-super local counting sort (1024 nodes, ~16K edges), 1024 threads.
// ---------------------------------------------------------------------------
__global__ __launch_bounds__(1024) void local_sort_kernel(
        const int* __restrict__ bucket_cnt,
        const int2* __restrict__ tmp,
        int* __restrict__ row_ptr,
        int2* __restrict__ sedge) {
    __shared__ int gsc[256];
    __shared__ int h[SPN];
    __shared__ int sc[SPN];
    __shared__ int cur[SPN];
    __shared__ int sbase, send;
    int b = blockIdx.x;
    int tid = threadIdx.x;
    int g = (tid < NSUP) ? bucket_cnt[tid] : 0;
    if (tid < 256) gsc[tid] = g;
    __syncthreads();
    for (int off = 1; off < 256; off <<= 1) {
        int t = (tid >= off && tid < 256) ? gsc[tid - off] : 0;
        __syncthreads();
        if (tid < 256) gsc[tid] += t;
        __syncthreads();
    }
    if (tid == 0) {
        int incl = gsc[b];
        int cb = bucket_cnt[b];
        sbase = incl - cb;
        send = incl;
        if (b == 0) row_ptr[NNODES] = NEDGES;
    }
    h[tid] = 0;
    __syncthreads();
    int base = sbase, end = send;
    for (int j = base + tid; j < end; j += 1024)
        atomicAdd(&h[(tmp[j].y >> 18) & (SPN - 1)], 1);
    __syncthreads();
    int c = h[tid];
    sc[tid] = c;
    __syncthreads();
    for (int off = 1; off < SPN; off <<= 1) {
        int t = (tid >= off) ? sc[tid - off] : 0;
        __syncthreads();
        sc[tid] += t;
        __syncthreads();
    }
    int excl = sc[tid] - c;
    cur[tid] = base + excl;
    int node = b * SPN + tid;
    if (node < NNODES) row_ptr[node] = base + excl;
    __syncthreads();
    for (int j = base + tid; j < end; j += 1024) {
        int2 e = tmp[j];
        int dl = (e.y >> 18) & (SPN - 1);
        int pos = atomicAdd(&cur[dl], 1);
        sedge[pos] = make_int2(e.y & 0x3FFFF, e.x);   // (src, val_bits)
    }
}

// ---------------------------------------------------------------------------
// spmm row body: 8 lanes per dst row, 16 B per lane, unroll x4
// ---------------------------------------------------------------------------
__device__ inline void spmm_row(int row, int k,
                                const int* __restrict__ row_ptr,
                                const int2* __restrict__ sedge,
                                const __half* __restrict__ cur,
                                __half* __restrict__ next) {
    int start = row_ptr[row];
    int end   = row_ptr[row + 1];
    float a0[8], a1[8], a2[8], a3[8];
    #pragma unroll
    for (int q = 0; q < 8; ++q) { a0[q] = 0.f; a1[q] = 0.f; a2[q] = 0.f; a3[q] = 0.f; }
    int j = start;
    for (; j + 4 <= end; j += 4) {
        int2 e0 = sedge[j];
        int2 e1 = sedge[j + 1];
        int2 e2 = sedge[j + 2];
        int2 e3 = sedge[j + 3];
        float4 r0 = *(const float4*)&cur[(long)e0.x * DIM + k];
        float4 r1 = *(const float4*)&cur[(long)e1.x * DIM + k];
        float4 r2 = *(const float4*)&cur[(long)e2.x * DIM + k];
        float4 r3 = *(const float4*)&cur[(long)e3.x * DIM + k];
        float v0 = __int_as_float(e0.y), v1 = __int_as_float(e1.y);
        float v2 = __int_as_float(e2.y), v3 = __int_as_float(e3.y);
        const __half2* h0 = (const __half2*)&r0;
        const __half2* h1 = (const __half2*)&r1;
        const __half2* h2 = (const __half2*)&r2;
        const __half2* h3 = (const __half2*)&r3;
        #pragma unroll
        for (int q = 0; q < 4; ++q) {
            float2 f0 = __half22float2(h0[q]);
            float2 f1 = __half22float2(h1[q]);
            float2 f2 = __half22float2(h2[q]);
            float2 f3 = __half22float2(h3[q]);
            a0[2*q]   += v0 * f0.x;  a0[2*q+1] += v0 * f0.y;
            a1[2*q]   += v1 * f1.x;  a1[2*q+1] += v1 * f1.y;
            a2[2*q]   += v2 * f2.x;  a2[2*q+1] += v2 * f2.y;
            a3[2*q]   += v3 * f3.x;  a3[2*q+1] += v3 * f3.y;
        }
    }
    for (; j < end; ++j) {
        int2 e = sedge[j];
        float v = __int_as_float(e.y);
        float4 r = *(const float4*)&cur[(long)e.x * DIM + k];
        const __half2* h = (const __half2*)&r;
        #pragma unroll
        for (int q = 0; q < 4; ++q) {
            float2 f = __half22float2(h[q]);
            a0[2*q]   += v * f.x;
            a0[2*q+1] += v * f.y;
        }
    }
    float4 st;
    __half2* sh = (__half2*)&st;
    #pragma unroll
    for (int q = 0; q < 4; ++q) {
        float lo = (a0[2*q]   + a1[2*q])   + (a2[2*q]   + a3[2*q]);
        float hi = (a0[2*q+1] + a1[2*q+1]) + (a2[2*q+1] + a3[2*q+1]);
        sh[q] = __floats2half2_rn(lo, hi);
    }
    *(float4*)&next[(long)row * DIM + k] = st;
}

// ---------------------------------------------------------------------------
// Layer 1 + mark tail: plain (non-atomic) flag stores, no worklist.
// ---------------------------------------------------------------------------
__global__ void spmm_mark_kernel(const int* __restrict__ row_ptr,
                                 const int2* __restrict__ sedge,
                                 const __half* __restrict__ cur,
                                 __half* __restrict__ next,
                                 const int* __restrict__ users,
                                 const int* __restrict__ items,
                                 int* __restrict__ flags) {
    if (blockIdx.x < SPMM_B) {
        long t = (long)blockIdx.x * 256 + threadIdx.x;
        int row = (int)(t >> 3);
        if (row >= NNODES) return;
        spmm_row(row, ((int)t & 7) * 8, row_ptr, sedge, cur, next);
    } else {
        int t = (blockIdx.x - SPMM_B) * 256 + threadIdx.x;
        int slot = t >> 4;
        if (slot >= 2 * BATCH) return;
        int lane16 = t & 15;
        int node = (slot < BATCH) ? users[slot] : USER_NUM + items[slot - BATCH];
        if (lane16 == 0) flags[node] = 1;        // plain store
        int start = row_ptr[node];
        int end   = row_ptr[node + 1];
        for (int j = start + lane16; j < end; j += 16)
            flags[sedge[j].x] = 1;               // plain store, dup-safe
    }
}

// ---------------------------------------------------------------------------
// Layer 2 flag-gated + sample_add(e1) tail.
// ---------------------------------------------------------------------------
__global__ void spmm_flag_sa_kernel(const int* __restrict__ row_ptr,
                                    const int2* __restrict__ sedge,
                                    const __half* __restrict__ cur,
                                    __half* __restrict__ next,
                                    const int* __restrict__ users,
                                    const int* __restrict__ items,
                                    float* __restrict__ acc_s,
                                    const int* __restrict__ flags) {
    if (blockIdx.x < SPMM_B) {
        long t = (long)blockIdx.x * 256 + threadIdx.x;
        int row = (int)(t >> 3);
        if (row >= NNODES) return;
        if (!flags[row]) return;                 // e2 not needed here
        spmm_row(row, ((int)t & 7) * 8, row_ptr, sedge, cur, next);
    } else {
        int t = (blockIdx.x - SPMM_B) * 256 + threadIdx.x;
        int slot = t >> 4;
        if (slot >= 2 * BATCH) return;
        int k = (t & 15) * 4;
        int node = (slot < BATCH) ? users[slot] : USER_NUM + items[slot - BATCH];
        float4 x = h4_to_f4(*(const float2*)&cur[(long)node * DIM + k]);
        long o = (long)slot * DIM + k;
        float4 a = *(float4*)&acc_s[o];
        a.x += x.x; a.y += x.y; a.z += x.z; a.w += x.w;
        *(float4*)&acc_s[o] = a;
    }
}

// ---------------------------------------------------------------------------
// pair_kernel: fuse sample_add(e2) + sampled e3 + dot + sigmoid.
// ---------------------------------------------------------------------------
__global__ __launch_bounds__(256) void pair_kernel(
        const int* __restrict__ row_ptr,
        const int2* __restrict__ sedge,
        const __half* __restrict__ tab,     // e2 table (valid at flagged rows)
        const int* __restrict__ users,
        const int* __restrict__ items,
        const float* __restrict__ acc_s,    // e0+e1
        float* __restrict__ out) {
    int t = blockIdx.x * 256 + threadIdx.x;
    int p = t >> 5;
    if (p >= BATCH) return;
    int sub = t & 31;
    int lane = threadIdx.x & 63;
    bool isU = (sub < 16);
    int k = (sub & 15) * 4;
    int node = isU ? users[p] : USER_NUM + items[p];
    int slot = isU ? p : BATCH + p;

    int start = row_ptr[node];
    int end   = row_ptr[node + 1];
    float4 s0 = make_float4(0.f, 0.f, 0.f, 0.f);
    float4 s1 = s0;
    int j = start;
    for (; j + 2 <= end; j += 2) {
        int2 e0 = sedge[j];
        int2 e1 = sedge[j + 1];
        float4 x0 = h4_to_f4(*(const float2*)&tab[(long)e0.x * DIM + k]);
        float4 x1 = h4_to_f4(*(const float2*)&tab[(long)e1.x * DIM + k]);
        float v0 = __int_as_float(e0.y), v1 = __int_as_float(e1.y);
        s0.x += v0 * x0.x; s0.y += v0 * x0.y; s0.z += v0 * x0.z; s0.w += v0 * x0.w;
        s1.x += v1 * x1.x; s1.y += v1 * x1.y; s1.z += v1 * x1.z; s1.w += v1 * x1.w;
    }
    for (; j < end; ++j) {
        int2 e = sedge[j];
        float v = __int_as_float(e.y);
        float4 x = h4_to_f4(*(const float2*)&tab[(long)e.x * DIM + k]);
        s0.x += v * x.x; s0.y += v * x.y; s0.z += v * x.z; s0.w += v * x.w;
    }
    float4 a = *(const float4*)&acc_s[(long)slot * DIM + k];
    float4 e2v = h4_to_f4(*(const float2*)&tab[(long)node * DIM + k]);
    a.x += e2v.x + s0.x + s1.x;
    a.y += e2v.y + s0.y + s1.y;
    a.z += e2v.z + s0.z + s1.z;
    a.w += e2v.w + s0.w + s1.w;

    int partner = (lane + 16) & 63;
    float bx = __shfl(a.x, partner);
    float by = __shfl(a.y, partner);
    float bz = __shfl(a.z, partner);
    float bw = __shfl(a.w, partner);
    float pd = a.x * bx + a.y * by + a.z * bz + a.w * bw;
    #pragma unroll
    for (int off = 1; off < 16; off <<= 1) pd += __shfl_xor(pd, off);
    if (sub == 0) {
        float gamma = pd * (1.0f / 16.0f);
        out[p] = 1.0f / (1.0f + __expf(-gamma));
    }
}

extern "C" void kernel_launch(void* const* d_in, const int* in_sizes, int n_in,
                              void* d_out, int out_size, void* d_ws, size_t ws_size,
                              hipStream_t stream) {
    const float* user_emb = (const float*)d_in[0];
    const float* item_emb = (const float*)d_in[1];
    const int*   edge_src = (const int*)d_in[2];
    const int*   edge_dst = (const int*)d_in[3];
    const float* edge_val = (const float*)d_in[4];
    const int*   users    = (const int*)d_in[5];
    const int*   items    = (const int*)d_in[6];
    float* out = (float*)d_out;

    const size_t tbl  = (size_t)NNODES * DIM * sizeof(float);   // 38.4 MB
    const size_t htbl = (size_t)NNODES * DIM * sizeof(__half);  // 19.2 MB
    char* w = (char*)d_ws;
    float*  acc_s       = (float*)w;   w += tbl;
    char*   bufA        = w;           w += tbl;   // tmp int2, dead after local_sort
    char*   bufB        = w;           w += tbl;   // tabA + tabB
    int2*   sedge       = (int2*)w;    w += (size_t)NEDGES * 8;
    int*    row_ptr     = (int*)w;     w += ((size_t)NNODES + 16) * 4;
    // zeroed region: bucket_cnt | fill | flags  (one memset)
    int*    bucket_cnt  = (int*)w;     w += ((size_t)NSUP + 8) * 4;
    int*    fill        = (int*)w;     w += ((size_t)NSUP + 8) * 4;
    int*    flags       = (int*)w;     w += (size_t)NNODES * 4;
    const size_t zero_bytes = (size_t)((char*)w - (char*)bucket_cnt);
    int*    blockhist   = (int*)w;     w += (size_t)NBLK * NSUPP * 4;  // 375 KB

    int2*   tmp   = (int2*)bufA;
    __half* tabA  = (__half*)bufB;
    __half* tabB  = (__half*)(bufB + htbl);

    // ---- memset: bucket_cnt + fill + flags ----
    hipMemsetAsync(bucket_cnt, 0, zero_bytes, stream);
    // ---- hist || init || sample_init ----
    mega1_kernel<<<NBLK + INIT_B + SAMP_B, 256, 0, stream>>>(
        edge_dst, bucket_cnt, blockhist,
        user_emb, item_emb, tabA, users, items, acc_s);
    // ---- partition (inline scan) ----
    partition_kernel<<<NBLK, 1024, 0, stream>>>(edge_src, edge_dst, edge_val,
                                                blockhist, bucket_cnt, fill, tmp);
    // ---- local sort (inline scan) ----
    local_sort_kernel<<<NSUP, 1024, 0, stream>>>(bucket_cnt, tmp, row_ptr, sedge);
    // ---- layer 1 (full) + plain-store mark tail ----
    spmm_mark_kernel<<<SPMM_B + MARK_B, 256, 0, stream>>>(
        row_ptr, sedge, tabA, tabB, users, items, flags);
    // ---- layer 2 flag-gated + sample_add(e1) tail ----
    spmm_flag_sa_kernel<<<SPMM_B + SAMP_B, 256, 0, stream>>>(
        row_ptr, sedge, tabB, tabA, users, items, acc_s, flags);
    // ---- sample_add(e2) + sampled e3 + dot + sigmoid ----
    pair_kernel<<<(BATCH * 32 + 255) / 256, 256, 0, stream>>>(
        row_ptr, sedge, tabA, users, items, acc_s, out);
}